// Round 12
// baseline (79.196 us; speedup 1.0000x reference)
//
#include <hip/hip_runtime.h>
#include <hip/hip_bf16.h>

typedef __bf16 bf16t;
typedef bf16t bf16x4 __attribute__((ext_vector_type(4)));
typedef bf16t bf16x8 __attribute__((ext_vector_type(8)));
typedef float f32x2 __attribute__((ext_vector_type(2)));
typedef float f32x4 __attribute__((ext_vector_type(4)));
typedef float f32x16 __attribute__((ext_vector_type(16)));
typedef unsigned short u16x8 __attribute__((ext_vector_type(8)));
typedef unsigned int u32x4 __attribute__((ext_vector_type(4)));

#define NB 2
#define NQ 2048
#define NK 2048
#define NH 16
#define ND 64
#define HD (NH * ND) /* 1024 */
#define KVBLK 64
#define NUNITS 512  /* B * H * (Q/128) */
#define SCALE_LOG2E 0.18033688011112042f
#define RESCALE_THR 8.0f

// ws layout: [0, 8MB) bf16 K, swizzle baked per 128B row;
//            [8MB, 16MB) bf16 V^T per head [64 d][2048 k], swizzle baked
//            per 128B tile-slice; [16MB, ...) split partials.
#define KWS_BYTES  8388608ULL
#define PRE_BYTES  16777216ULL
#define HEAD_BYTES 262144ULL
#define OPART_BYTES(n) ((size_t)(n) * 8388608ULL)
#define ML_BYTES(n)    ((size_t)(n) * 524288ULL)

// R12: remove per-tile staging work. Pre-pass kernels bake bf16 K and
// transposed V into d_ws with the XOR swizzle applied in the stored layout
// (linear LDS dest + inverse-swizzled source, m201 pattern). Scan staging is
// then 4x global_load_lds dwordx4 / thread / tile: no regs, no cvt, no
// ds_write. Loads for t+1 issue right after the tile barrier -> full-tile
// latency cover; __syncthreads' vmcnt(0) is the completion fence.
__device__ inline unsigned cvt_pk_bf16(float a, float b) {
    unsigned r;
    asm("v_cvt_pk_bf16_f32 %0, %1, %2" : "=v"(r) : "v"(a), "v"(b));
    return r;  // lo16 = bf16(a), hi16 = bf16(b)
}

__device__ inline void plswap(unsigned& a, unsigned& b) {
#if __has_builtin(__builtin_amdgcn_permlane32_swap)
    auto r = __builtin_amdgcn_permlane32_swap(a, b, false, false);
    a = r[0]; b = r[1];
#else
    const unsigned as = __shfl_xor((int)a, 32);
    const unsigned bs = __shfl_xor((int)b, 32);
    const bool lh = (threadIdx.x & 32) != 0;
    const unsigned na = lh ? bs : a;
    const unsigned nb = lh ? b : as;
    a = na; b = nb;
#endif
}

__device__ inline void gl_lds16(const void* g, void* l) {
    __builtin_amdgcn_global_load_lds(
        (const __attribute__((address_space(1))) unsigned int*)g,
        (__attribute__((address_space(3))) unsigned int*)l, 16, 0, 0);
}

// ---- pre-pass: K f32 -> bf16, row-swizzled. One 16B out-chunk per thread.
__global__ __launch_bounds__(256)
void prep_k(const float* __restrict__ ks, char* __restrict__ ws)
{
    const int g    = blockIdx.x * 256 + threadIdx.x;   // 524288 chunks
    const int c8   = g & 7;
    const int row  = g >> 3;            // head*2048 + k
    const int k    = row & 2047;
    const int head = row >> 11;         // b*16 + h
    const int b    = head >> 4;
    const int h    = head & 15;

    const int y  = c8 << 4;                     // out byte in 128B row
    const int d2 = y ^ ((k & 7) << 4);          // src byte in bf16 row
    const int e0 = d2 >> 1;                     // src f32 element (mult of 8)

    const float* src = ks + (((size_t)b * NK + k) * NH + h) * ND + e0;
    f32x4 lo = *reinterpret_cast<const f32x4*>(src);
    f32x4 hi = *reinterpret_cast<const f32x4*>(src + 4);
    u16x8 o;
#pragma unroll
    for (int e = 0; e < 4; ++e) {
        o[e]     = __builtin_bit_cast(unsigned short, (bf16t)lo[e]);
        o[4 + e] = __builtin_bit_cast(unsigned short, (bf16t)hi[e]);
    }
    *reinterpret_cast<u16x8*>(ws + (size_t)row * 128 + y) = o;
}

// ---- pre-pass: V f32 -> bf16 transposed [d][k], tile-slice swizzled.
__global__ __launch_bounds__(256)
void prep_v(const float* __restrict__ vs, char* __restrict__ ws)
{
    __shared__ __align__(16) unsigned short lt[64][64];   // [d][k] 8KB

    const int bid = blockIdx.x;         // 1024 = 2*16*32
    const int kt  = bid & 31;
    const int h   = (bid >> 5) & 15;
    const int b   = bid >> 9;
    const int tid = threadIdx.x;

    const int kr = tid >> 2;            // k-row 0..63
    const int c4 = tid & 3;             // 16-float column group
    const float* src = vs + (((size_t)b * NK + kt * 64 + kr) * NH + h) * ND + c4 * 16;
#pragma unroll
    for (int i = 0; i < 4; ++i) {
        f32x4 v = *reinterpret_cast<const f32x4*>(src + 4 * i);
#pragma unroll
        for (int e = 0; e < 4; ++e)
            lt[c4 * 16 + 4 * i + e][kr] =
                __builtin_bit_cast(unsigned short, (bf16t)v[e]);
    }
    __syncthreads();

    char* dst = ws + KWS_BYTES + (size_t)(b * NH + h) * HEAD_BYTES;
#pragma unroll
    for (int r = 0; r < 2; ++r) {
        const int L = r * 4096 + tid * 16;
        const int d = L >> 7;
        const int y = L & 127;
        u16x8 v = *reinterpret_cast<const u16x8*>(
            (const char*)lt + d * 128 + (y ^ ((d & 7) << 4)));
        *reinterpret_cast<u16x8*>(dst + (size_t)d * 4096 + kt * 128 + y) = v;
    }
}

template <int NSPLIT>
__global__ __launch_bounds__(256)
void scan_attn(const float* __restrict__ qs, const int* __restrict__ vlen,
               float* __restrict__ out, char* __restrict__ ws)
{
    const int bid = blockIdx.x;
    const int x    = bid & 7;
    const int jj   = bid >> 3;
    const int b    = jj & 1;
    const int code = x | ((jj >> 1) << 3);       // [0, 256*NSPLIT)
    const int qt   = code / (16 * NSPLIT);
    const int rr   = code % (16 * NSPLIT);
    const int h    = rr / NSPLIT;
    const int s    = rr % NSPLIT;
    const int uidx = ((b * NH + h) << 4) + qt;

    const int tid  = threadIdx.x;
    const int wq   = tid >> 6;
    const int lane = tid & 63;
    const int ql   = lane & 31;
    const int lh   = lane >> 5;
    const int swq  = (ql & 7) << 4;
    const int q    = qt * 128 + wq * 32 + ql;

    const int nkv    = vlen[b];
    const int ntiles = (nkv + KVBLK - 1) >> 6;
    const int rem    = nkv & 63;
    const int tlo    = (ntiles * s) / NSPLIT;
    const int thi    = (ntiles * (s + 1)) / NSPLIT;

    const float* qptr = qs + ((size_t)b * NQ + q) * HD + h * ND;
    const size_t hoff = (size_t)(b * NH + h) * HEAD_BYTES;
    const char*  kws  = ws + hoff;
    const char*  vtws = ws + KWS_BYTES + hoff;

    // double-buffered [ K tile 8KB | V^T tile 8KB ] = 32 KB
    __shared__ __align__(16) char smem[2][16384];

    // ---- Q fragments (B-operand), scale folded in
    bf16x8 qf[4];
#pragma unroll
    for (int c = 0; c < 4; ++c) {
        const float* p = qptr + 16 * c + 8 * lh;
        f32x4 lo4 = *reinterpret_cast<const f32x4*>(p);
        f32x4 hi4 = *reinterpret_cast<const f32x4*>(p + 4);
#pragma unroll
        for (int e = 0; e < 4; ++e) {
            qf[c][e]     = (bf16t)(lo4[e] * SCALE_LOG2E);
            qf[c][4 + e] = (bf16t)(hi4[e] * SCALE_LOG2E);
        }
    }

    // ---- async DMA staging: 4x global_load_lds(16B) per thread per tile
    auto stage = [&](int buf, int kb) {
        const char* ks_ = kws + (size_t)kb * 128;   // contiguous 8KB
        const char* vs_ = vtws + (size_t)kb * 2;    // 128B slice per 4KB row
        char* kd = smem[buf];
        char* vd = smem[buf] + 8192;
#pragma unroll
        for (int r = 0; r < 2; ++r) {
            const int L = r * 4096 + tid * 16;
            gl_lds16(ks_ + L, kd + L);
            gl_lds16(vs_ + (size_t)(L >> 7) * 4096 + (L & 127), vd + L);
        }
    };

    float mrun = -__builtin_inff();
    float lrun = 0.0f;
    f32x16 o[2] = {};

    if (tlo < thi) stage(0, tlo << 6);
    __syncthreads();    // vmcnt(0): first tile staged

    int cur = 0;
    for (int t = tlo; t < thi; ++t) {
        const int kb = t << 6;
        const bool has_next = (t + 1) < thi;
        if (has_next) stage(cur ^ 1, (t + 1) << 6);   // full-tile latency cover

        const char* kbuf = smem[cur];
        const char* vbuf = smem[cur] + 8192;

#pragma unroll
        for (int h2 = 0; h2 < 2; ++h2) {
            // S^T = K_half . Q^T (log2 domain); s_[r]: q=ql,
            // k = kb + 32*h2 + (r&3) + 8*(r>>2) + 4*lh
            f32x16 s_ = {};
            const char* krow = kbuf + (32 * h2 + ql) * 128;
#pragma unroll
            for (int c = 0; c < 4; ++c) {
                bf16x8 kf = *reinterpret_cast<const bf16x8*>(
                    krow + ((32 * c + 16 * lh) ^ swq));
                s_ = __builtin_amdgcn_mfma_f32_32x32x16_bf16(kf, qf[c], s_, 0, 0, 0);
            }

            if (rem && t == ntiles - 1) {
                const int krem = nkv - kb;
#pragma unroll
                for (int r = 0; r < 16; ++r)
                    if (32 * h2 + (r & 3) + 8 * (r >> 2) + 4 * lh >= krem)
                        s_[r] = -__builtin_inff();
            }

            float pmax = -__builtin_inff();
#pragma unroll
            for (int r = 0; r < 16; ++r) pmax = fmaxf(pmax, s_[r]);
            pmax = fmaxf(pmax, __shfl_xor(pmax, 32));

            if (!__all(pmax <= mrun + RESCALE_THR)) {   // defer-max (T13)
                const float mnew  = fmaxf(mrun, pmax);
                const float alpha = exp2f(mrun - mnew);
                lrun *= alpha;
                o[0] *= alpha;
                o[1] *= alpha;
                mrun = mnew;
            }

            float ps = 0.0f;
#pragma unroll
            for (int r = 0; r < 16; ++r) {
                const float pv = exp2f(s_[r] - mrun);
                s_[r] = pv;
                ps += pv;
            }
            ps += __shfl_xor(ps, 32);
            lrun += ps;

            bf16x8 pf[2];
#pragma unroll
            for (int cc = 0; cc < 2; ++cc) {
                const int r0 = cc * 8;
                unsigned a0 = cvt_pk_bf16(s_[r0 + 0], s_[r0 + 1]);
                unsigned b0 = cvt_pk_bf16(s_[r0 + 4], s_[r0 + 5]);
                plswap(a0, b0);
                unsigned a1 = cvt_pk_bf16(s_[r0 + 2], s_[r0 + 3]);
                unsigned b1 = cvt_pk_bf16(s_[r0 + 6], s_[r0 + 7]);
                plswap(a1, b1);
                pf[cc] = __builtin_bit_cast(bf16x8, (u32x4){a0, a1, b0, b1});
            }

#pragma unroll
            for (int dt = 0; dt < 2; ++dt) {
                const char* vrow = vbuf + (32 * dt + ql) * 128;
#pragma unroll
                for (int cc = 0; cc < 2; ++cc) {
                    const int c = 2 * h2 + cc;
                    bf16x8 vf = *reinterpret_cast<const bf16x8*>(
                        vrow + ((32 * c + 16 * lh) ^ swq));
                    o[dt] = __builtin_amdgcn_mfma_f32_32x32x16_bf16(vf, pf[cc], o[dt], 0, 0, 0);
                }
            }
        }

        __syncthreads();    // vmcnt(0): next tile staged; cur free to overwrite
        cur ^= 1;
    }

    char* part = ws + PRE_BYTES;
    if (NSPLIT == 1) {
        const float inv = 1.0f / lrun;
        float* op = out + ((size_t)b * NQ + q) * HD + h * ND;
#pragma unroll
        for (int dt = 0; dt < 2; ++dt)
#pragma unroll
            for (int rg = 0; rg < 4; ++rg) {
                f32x4 w;
#pragma unroll
                for (int e = 0; e < 4; ++e) w[e] = o[dt][4 * rg + e] * inv;
                *reinterpret_cast<f32x4*>(op + 32 * dt + 8 * rg + 4 * lh) = w;
            }
    } else {
        const int p = uidx * NSPLIT + s;
        bf16t* op = (bf16t*)part + ((size_t)p * 128 + wq * 32 + ql) * 64;
#pragma unroll
        for (int dt = 0; dt < 2; ++dt)
#pragma unroll
            for (int rg = 0; rg < 4; ++rg) {
                bf16x4 w;
#pragma unroll
                for (int e = 0; e < 4; ++e) w[e] = (bf16t)o[dt][4 * rg + e];
                *reinterpret_cast<bf16x4*>(op + 32 * dt + 8 * rg + 4 * lh) = w;
            }
        if (lh == 0) {
            f32x2* ml = (f32x2*)(part + OPART_BYTES(NSPLIT));
            ml[p * 128 + wq * 32 + ql] = (f32x2){mrun, lrun};
        }
    }
}

template <int NSPLIT>
__global__ __launch_bounds__(256)
void merge_attn(const char* __restrict__ part, float* __restrict__ out)
{
    const int u  = blockIdx.x;
    const int b  = u >> 8;
    const int h  = (u >> 4) & 15;
    const int qt = u & 15;
    const int tid = threadIdx.x;
    const int q  = tid >> 1;
    const int dh = (tid & 1) * 32;

    const bf16t* opart = (const bf16t*)part;
    const f32x2* ml    = (const f32x2*)(part + OPART_BYTES(NSPLIT));

    float m_s[NSPLIT], l_s[NSPLIT];
    float M = -__builtin_inff();
#pragma unroll
    for (int s = 0; s < NSPLIT; ++s) {
        f32x2 v = ml[(u * NSPLIT + s) * 128 + q];
        m_s[s] = v[0]; l_s[s] = v[1];
        M = fmaxf(M, v[0]);
    }
    float L = 0.0f, w_s[NSPLIT];
#pragma unroll
    for (int s = 0; s < NSPLIT; ++s) {
        w_s[s] = exp2f(m_s[s] - M);
        L += w_s[s] * l_s[s];
    }
    const float inv = 1.0f / L;

    float acc[32];
#pragma unroll
    for (int e = 0; e < 32; ++e) acc[e] = 0.0f;
#pragma unroll
    for (int s = 0; s < NSPLIT; ++s) {
        const bf16t* op = opart + ((size_t)(u * NSPLIT + s) * 128 + q) * 64 + dh;
#pragma unroll
        for (int c = 0; c < 4; ++c) {
            bf16x8 v8 = *reinterpret_cast<const bf16x8*>(op + 8 * c);
#pragma unroll
            for (int e = 0; e < 8; ++e)
                acc[8 * c + e] += w_s[s] * (float)v8[e];
        }
    }

    float* op = out + ((size_t)b * NQ + qt * 128 + q) * HD + h * ND + dh;
#pragma unroll
    for (int c = 0; c < 8; ++c) {
        f32x4 st;
#pragma unroll
        for (int e = 0; e < 4; ++e) st[e] = acc[4 * c + e] * inv;
        *reinterpret_cast<f32x4*>(op + 4 * c) = st;
    }
}

extern "C" void kernel_launch(void* const* d_in, const int* in_sizes, int n_in,
                              void* d_out, int out_size, void* d_ws, size_t ws_size,
                              hipStream_t stream)
{
    const float* qs   = (const float*)d_in[0];
    const float* ks   = (const float*)d_in[1];
    const float* vs   = (const float*)d_in[2];
    const int*   vlen = (const int*)d_in[3];
    float* out = (float*)d_out;
    char*  ws  = (char*)d_ws;

    const size_t need2 = PRE_BYTES + OPART_BYTES(2) + ML_BYTES(2);  // ~34.6 MB
    const size_t need1 = PRE_BYTES;                                 // 16.8 MB

    prep_k<<<2048, 256, 0, stream>>>(ks, ws);
    prep_v<<<1024, 256, 0, stream>>>(vs, ws);

    if (ws_size >= need2) {
        scan_attn<2><<<NUNITS * 2, 256, 0, stream>>>(qs, vlen, out, ws);
        merge_attn<2><<<NUNITS, 256, 0, stream>>>(ws + PRE_BYTES, out);
    } else if (ws_size >= need1) {
        scan_attn<1><<<NUNITS, 256, 0, stream>>>(qs, vlen, out, ws);
    }
}